// Round 4
// baseline (535.061 us; speedup 1.0000x reference)
//
#include <hip/hip_runtime.h>
#include <math.h>

// Problem constants (from reference)
#define TT 10
#define SS 10
#define RR 2000
#define KK 100
#define OO 500
#define PP (TT*SS*RR)          // 200000 particles
#define NT16 12500             // 16-row tiles
#define NT 7                   // 7 N-tiles of 16 cols -> 112 padded assemblages
#define WPB 3                  // waves per block (24.6 KB LDS -> 6 blocks/CU = 18 waves)
#define BLOCKT (WPB*64)
#define NBLK 1536              // 4608 waves total (= 18 waves/CU * 256 CU)
#define TOTW (NBLK*WPB)
#define EPSF 1e-6f

typedef float        f32x4  __attribute__((ext_vector_type(4)));
typedef unsigned int u32x4  __attribute__((ext_vector_type(4)));
typedef unsigned int u32x2  __attribute__((ext_vector_type(2)));
typedef __bf16       bf16x8 __attribute__((ext_vector_type(8)));
typedef __bf16       bf16x4 __attribute__((ext_vector_type(4)));

union BFU { bf16x8 v; u32x4 q; };
union BF4 { bf16x4 v; u32x2 q; };

// ---------------------------------------------------------------------------
// Prep: per theta row: softmax -> out[1..]; log(theta+eps) bf16 written to ws
// in EXACT MFMA B-fragment order: word[(K*7+nt)*64 + g*16 + lo] =
// logtheta[nt*16+lo][K*32+g*8 .. +8].  Pad rows 100..111 -> zeros.
// Also: beta copy -> out[50001..), out[0] = 0.
// ---------------------------------------------------------------------------
__global__ __launch_bounds__(64) void mcspace_prep(
    const float* __restrict__ theta_params,
    const float* __restrict__ beta,
    float* __restrict__ out,
    u32x4* __restrict__ Bf)
{
    __shared__ float row[512];
    const int b  = blockIdx.x;
    const int ln = threadIdx.x;
    if (b < 112) {
        const int nt = b >> 4, lo = b & 15;
        const int ko = ln >> 2, g = ln & 3;
        if (b < KK) {
            const float* tp = theta_params + b * OO;
            float x[8];
            #pragma unroll
            for (int j = 0; j < 8; ++j) {
                int o = ln + 64 * j;
                x[j] = (o < OO) ? tp[o] : -INFINITY;
            }
            float mx = x[0];
            #pragma unroll
            for (int j = 1; j < 8; ++j) mx = fmaxf(mx, x[j]);
            #pragma unroll
            for (int w = 1; w < 64; w <<= 1) mx = fmaxf(mx, __shfl_xor(mx, w));
            float e[8], sm = 0.f;
            #pragma unroll
            for (int j = 0; j < 8; ++j) { e[j] = __expf(x[j] - mx); sm += e[j]; }
            #pragma unroll
            for (int w = 1; w < 64; w <<= 1) sm += __shfl_xor(sm, w);
            const float inv = 1.f / sm;
            #pragma unroll
            for (int j = 0; j < 8; ++j) {
                int o = ln + 64 * j;
                float th = e[j] * inv;            // 0 for o >= 500
                if (o < OO) out[1 + b * OO + o] = th;
                row[o] = th;
            }
            __syncthreads();
            BFU w8;
            #pragma unroll
            for (int i = 0; i < 8; ++i)
                w8.v[i] = (__bf16)__logf(row[ko * 32 + g * 8 + i] + EPSF);
            Bf[(ko * 7 + nt) * 64 + g * 16 + lo] = w8.q;
        } else {
            Bf[(ko * 7 + nt) * 64 + g * 16 + lo] = (u32x4){0u, 0u, 0u, 0u};
        }
    } else {
        int idx = (b - 112) * 64 + ln;
        if (idx < KK * TT * SS) out[1 + KK * OO + idx] = beta[idx];
        if (b == 112 && ln == 0) out[0] = 0.f;
    }
}

// ---------------------------------------------------------------------------
// Main: per-wave autonomous 16-row tiles. A: contiguous global stream ->
// private swizzled LDS buffer (half-K double pass). B: fragment-ordered bf16
// from ws (L2-resident). No __syncthreads in the hot loop.
// ---------------------------------------------------------------------------
__global__ __launch_bounds__(BLOCKT, 5) void mcspace_main(
    const float* __restrict__ counts,
    const float* __restrict__ beta,
    const u32x4* __restrict__ Bf,
    float* __restrict__ out)
{
    __shared__ char Abuf[WPB][8192];   // per-wave [16 rows][512 B] swizzled bf16
    __shared__ float red[WPB];

    const int tid = threadIdx.x;
    const int wv  = tid >> 6;
    const int ln  = tid & 63;
    const int lo  = ln & 15;
    const int g   = ln >> 4;
    char* wb = Abuf[wv];

    const int xr    = (lo & 7) << 4;
    const int rdoff = lo * 512;

    float wacc = 0.f;
    const int gw = blockIdx.x * WPB + wv;

    for (int tile = gw; tile < NT16; tile += TOTW) {
        const int ts = tile / 125;                  // 125 tiles per (t,s)
        const float* base = counts + (long)tile * (16 * OO);

        f32x4 acc[NT];
        #pragma unroll
        for (int nt = 0; nt < NT; ++nt) acc[nt] = (f32x4){0.f, 0.f, 0.f, 0.f};

        for (int h = 0; h < 2; ++h) {
            const int c0  = h * 256;
            const int lim = h ? 60 : 63;            // h=1: cols 256..499 = 61 chunks

            // ---- stage 16 rows (1 KB contiguous per row-load) ----
            #pragma unroll
            for (int rb = 0; rb < 2; ++rb) {
                f32x4 v[8];
                #pragma unroll
                for (int r = 0; r < 8; ++r) {
                    int row = rb * 8 + r;
                    if (ln <= lim)
                        v[r] = *(const f32x4*)(base + row * OO + c0 + ln * 4);
                }
                #pragma unroll
                for (int r = 0; r < 8; ++r) {
                    int row = rb * 8 + r;
                    BF4 w;
                    if (ln <= lim) {
                        #pragma unroll
                        for (int q = 0; q < 4; ++q) w.v[q] = (__bf16)v[r][q];
                    } else {
                        w.q = (u32x2){0u, 0u};
                    }
                    *(u32x2*)(wb + row * 512 + ((ln * 8) ^ ((row & 7) << 4))) = w.q;
                }
            }

            // ---- 8 K-steps: 1 A ds_read + 7 B L2-loads + 7 MFMA ----
            #pragma unroll
            for (int ko = 0; ko < 8; ++ko) {
                BFU av;
                av.q = *(const u32x4*)(wb + rdoff + ((ko * 64 + g * 16) ^ xr));
                const u32x4* bp = Bf + ((h * 8 + ko) * 7) * 64 + ln;
                #pragma unroll
                for (int nt = 0; nt < NT; ++nt) {
                    BFU bv; bv.q = bp[nt * 64];
                    acc[nt] = __builtin_amdgcn_mfma_f32_16x16x32_bf16(av.v, bv.v, acc[nt], 0, 0, 0);
                }
            }
        }

        // ---- beta-weighted logsumexp (in-register, R1-verified layout) ----
        float bet[NT];
        #pragma unroll
        for (int nt = 0; nt < NT; ++nt) {
            int j = nt * 16 + lo;
            bet[nt] = (j < KK) ? beta[j * (TT * SS) + ts] : 0.f;
        }
        float mrow[4] = {-INFINITY, -INFINITY, -INFINITY, -INFINITY};
        #pragma unroll
        for (int nt = 0; nt < NT; ++nt) {
            const bool valid = (nt * 16 + lo) < KK;
            #pragma unroll
            for (int r = 0; r < 4; ++r)
                mrow[r] = fmaxf(mrow[r], valid ? acc[nt][r] : -INFINITY);
        }
        #pragma unroll
        for (int w = 1; w < 16; w <<= 1) {
            #pragma unroll
            for (int r = 0; r < 4; ++r)
                mrow[r] = fmaxf(mrow[r], __shfl_xor(mrow[r], w));
        }
        float srow[4] = {0.f, 0.f, 0.f, 0.f};
        #pragma unroll
        for (int nt = 0; nt < NT; ++nt) {
            const bool valid = (nt * 16 + lo) < KK;
            #pragma unroll
            for (int r = 0; r < 4; ++r)
                srow[r] += bet[nt] * __expf(valid ? (acc[nt][r] - mrow[r]) : -INFINITY);
        }
        #pragma unroll
        for (int w = 1; w < 16; w <<= 1) {
            #pragma unroll
            for (int r = 0; r < 4; ++r)
                srow[r] += __shfl_xor(srow[r], w);
        }
        if (lo == 0) {
            #pragma unroll
            for (int r = 0; r < 4; ++r)
                wacc += mrow[r] + __logf(srow[r] + EPSF);
        }
    }

    // ---- deterministic block reduction, one atomic per block ----
    #pragma unroll
    for (int w = 1; w < 64; w <<= 1) wacc += __shfl_xor(wacc, w);
    if (ln == 0) red[wv] = wacc;
    __syncthreads();
    if (tid == 0) {
        float s = 0.f;
        #pragma unroll
        for (int i = 0; i < WPB; ++i) s += red[i];
        atomicAdd(out, -s);   // elbo_loss = -loglik
    }
}

extern "C" void kernel_launch(void* const* d_in, const int* in_sizes, int n_in,
                              void* d_out, int out_size, void* d_ws, size_t ws_size,
                              hipStream_t stream)
{
    (void)in_sizes; (void)n_in; (void)ws_size; (void)out_size;
    const float* counts       = (const float*)d_in[0];
    const float* theta_params = (const float*)d_in[1];
    const float* beta         = (const float*)d_in[2];
    float* out = (float*)d_out;
    u32x4* Bf  = (u32x4*)d_ws;        // 112 KB fragment-ordered log-theta bf16

    // prep: 112 theta/Bf blocks + 157 beta-copy blocks
    mcspace_prep<<<dim3(112 + (KK * TT * SS + 63) / 64), dim3(64), 0, stream>>>(
        theta_params, beta, out, Bf);
    // main: 1536 blocks x 3 waves, per-wave tile streams
    mcspace_main<<<dim3(NBLK), dim3(BLOCKT), 0, stream>>>(
        counts, beta, Bf, out);
}

// Round 5
// 236.965 us; speedup vs baseline: 2.2580x; 2.2580x over previous
//
#include <hip/hip_runtime.h>
#include <math.h>

// Problem constants (from reference)
#define TT 10
#define SS 10
#define RR 2000
#define KK 100
#define OO 500
#define PP (TT*SS*RR)          // 200000 particles
#define NT16 12500             // 16-row tiles
#define NT 7                   // 7 N-tiles of 16 cols -> 112 padded assemblages
#define WPB 4                  // waves per block (32.8 KB LDS -> 4 blocks/CU)
#define BLOCKT (WPB*64)        // 256 threads
#define NBLK 1024              // 4096 waves total
#define TOTW (NBLK*WPB)
#define EPSF 1e-6f

typedef float        f32x4  __attribute__((ext_vector_type(4)));
typedef unsigned int u32x4  __attribute__((ext_vector_type(4)));
typedef unsigned int u32x2  __attribute__((ext_vector_type(2)));
typedef __bf16       bf16x8 __attribute__((ext_vector_type(8)));
typedef __bf16       bf16x4 __attribute__((ext_vector_type(4)));

union BFU { bf16x8 v; u32x4 q; };
union BF4 { bf16x4 v; u32x2 q; };

// ---------------------------------------------------------------------------
// Prep: per theta row: softmax -> out[1..]; log(theta+eps) bf16 written to ws
// in EXACT MFMA B-fragment order: word[(K*7+nt)*64 + g*16 + lo] =
// logtheta[nt*16+lo][K*32+g*8 .. +8].  Pad rows 100..111 -> zeros.
// Also: beta copy -> out[50001..), out[0] = 0.
// ---------------------------------------------------------------------------
__global__ __launch_bounds__(64) void mcspace_prep(
    const float* __restrict__ theta_params,
    const float* __restrict__ beta,
    float* __restrict__ out,
    u32x4* __restrict__ Bf)
{
    __shared__ float row[512];
    const int b  = blockIdx.x;
    const int ln = threadIdx.x;
    if (b < 112) {
        const int nt = b >> 4, lo = b & 15;
        const int ko = ln >> 2, g = ln & 3;
        if (b < KK) {
            const float* tp = theta_params + b * OO;
            float x[8];
            #pragma unroll
            for (int j = 0; j < 8; ++j) {
                int o = ln + 64 * j;
                x[j] = (o < OO) ? tp[o] : -INFINITY;
            }
            float mx = x[0];
            #pragma unroll
            for (int j = 1; j < 8; ++j) mx = fmaxf(mx, x[j]);
            #pragma unroll
            for (int w = 1; w < 64; w <<= 1) mx = fmaxf(mx, __shfl_xor(mx, w));
            float e[8], sm = 0.f;
            #pragma unroll
            for (int j = 0; j < 8; ++j) { e[j] = __expf(x[j] - mx); sm += e[j]; }
            #pragma unroll
            for (int w = 1; w < 64; w <<= 1) sm += __shfl_xor(sm, w);
            const float inv = 1.f / sm;
            #pragma unroll
            for (int j = 0; j < 8; ++j) {
                int o = ln + 64 * j;
                float th = e[j] * inv;            // 0 for o >= 500
                if (o < OO) out[1 + b * OO + o] = th;
                row[o] = th;
            }
            __syncthreads();
            BFU w8;
            #pragma unroll
            for (int i = 0; i < 8; ++i)
                w8.v[i] = (__bf16)__logf(row[ko * 32 + g * 8 + i] + EPSF);
            Bf[(ko * 7 + nt) * 64 + g * 16 + lo] = w8.q;
        } else {
            Bf[(ko * 7 + nt) * 64 + g * 16 + lo] = (u32x4){0u, 0u, 0u, 0u};
        }
    } else {
        int idx = (b - 112) * 64 + ln;
        if (idx < KK * TT * SS) out[1 + KK * OO + idx] = beta[idx];
        if (b == 112 && ln == 0) out[0] = 0.f;
    }
}

// ---------------------------------------------------------------------------
// Main: per-wave autonomous 16-row tiles. A: contiguous global stream ->
// private swizzled LDS buffer (half-K double pass, 4-row reg groups).
// B: fragment-ordered bf16 from ws (L2-resident). No hot-loop barriers.
// ---------------------------------------------------------------------------
__global__ __launch_bounds__(BLOCKT) void mcspace_main(
    const float* __restrict__ counts,
    const float* __restrict__ beta,
    const u32x4* __restrict__ Bf,
    float* __restrict__ out)
{
    __shared__ char Abuf[WPB][8192];   // per-wave [16 rows][512 B] swizzled bf16
    __shared__ float red[WPB];

    const int tid = threadIdx.x;
    const int wv  = tid >> 6;
    const int ln  = tid & 63;
    const int lo  = ln & 15;
    const int g   = ln >> 4;
    char* wb = Abuf[wv];

    const int xr    = (lo & 7) << 4;
    const int rdoff = lo * 512;

    float wacc = 0.f;
    const int gw = blockIdx.x * WPB + wv;

    for (int tile = gw; tile < NT16; tile += TOTW) {
        const int ts = tile / 125;                  // 125 tiles per (t,s)
        const float* base = counts + (long)tile * (16 * OO);

        f32x4 acc[NT];
        #pragma unroll
        for (int nt = 0; nt < NT; ++nt) acc[nt] = (f32x4){0.f, 0.f, 0.f, 0.f};

        for (int h = 0; h < 2; ++h) {
            const int c0  = h * 256;
            const int lim = h ? 60 : 63;            // h=1: cols 256..499 = 61 chunks

            // ---- stage 16 rows, 4-row register groups (contiguous 1 KB/row) ----
            #pragma unroll
            for (int rg = 0; rg < 4; ++rg) {
                f32x4 v[4];
                #pragma unroll
                for (int r = 0; r < 4; ++r) {
                    int row = rg * 4 + r;
                    if (ln <= lim)
                        v[r] = *(const f32x4*)(base + row * OO + c0 + ln * 4);
                }
                #pragma unroll
                for (int r = 0; r < 4; ++r) {
                    int row = rg * 4 + r;
                    BF4 w;
                    if (ln <= lim) {
                        #pragma unroll
                        for (int q = 0; q < 4; ++q) w.v[q] = (__bf16)v[r][q];
                    } else {
                        w.q = (u32x2){0u, 0u};
                    }
                    *(u32x2*)(wb + row * 512 + ((ln * 8) ^ ((row & 7) << 4))) = w.q;
                }
            }

            // ---- 8 K-steps: 1 A ds_read + 7 B L2-loads + 7 MFMA ----
            #pragma unroll
            for (int ko = 0; ko < 8; ++ko) {
                BFU av;
                av.q = *(const u32x4*)(wb + rdoff + ((ko * 64 + g * 16) ^ xr));
                const u32x4* bp = Bf + ((h * 8 + ko) * 7) * 64 + ln;
                #pragma unroll
                for (int nt = 0; nt < NT; ++nt) {
                    BFU bv; bv.q = bp[nt * 64];
                    acc[nt] = __builtin_amdgcn_mfma_f32_16x16x32_bf16(av.v, bv.v, acc[nt], 0, 0, 0);
                }
            }
        }

        // ---- beta-weighted logsumexp (in-register, R1-verified layout) ----
        float bet[NT];
        #pragma unroll
        for (int nt = 0; nt < NT; ++nt) {
            int j = nt * 16 + lo;
            bet[nt] = (j < KK) ? beta[j * (TT * SS) + ts] : 0.f;
        }
        float mrow[4] = {-INFINITY, -INFINITY, -INFINITY, -INFINITY};
        #pragma unroll
        for (int nt = 0; nt < NT; ++nt) {
            const bool valid = (nt * 16 + lo) < KK;
            #pragma unroll
            for (int r = 0; r < 4; ++r)
                mrow[r] = fmaxf(mrow[r], valid ? acc[nt][r] : -INFINITY);
        }
        #pragma unroll
        for (int w = 1; w < 16; w <<= 1) {
            #pragma unroll
            for (int r = 0; r < 4; ++r)
                mrow[r] = fmaxf(mrow[r], __shfl_xor(mrow[r], w));
        }
        float srow[4] = {0.f, 0.f, 0.f, 0.f};
        #pragma unroll
        for (int nt = 0; nt < NT; ++nt) {
            const bool valid = (nt * 16 + lo) < KK;
            #pragma unroll
            for (int r = 0; r < 4; ++r)
                srow[r] += bet[nt] * __expf(valid ? (acc[nt][r] - mrow[r]) : -INFINITY);
        }
        #pragma unroll
        for (int w = 1; w < 16; w <<= 1) {
            #pragma unroll
            for (int r = 0; r < 4; ++r)
                srow[r] += __shfl_xor(srow[r], w);
        }
        if (lo == 0) {
            #pragma unroll
            for (int r = 0; r < 4; ++r)
                wacc += mrow[r] + __logf(srow[r] + EPSF);
        }
    }

    // ---- deterministic block reduction, one atomic per block ----
    #pragma unroll
    for (int w = 1; w < 64; w <<= 1) wacc += __shfl_xor(wacc, w);
    if (ln == 0) red[wv] = wacc;
    __syncthreads();
    if (tid == 0) {
        float s = 0.f;
        #pragma unroll
        for (int i = 0; i < WPB; ++i) s += red[i];
        atomicAdd(out, -s);   // elbo_loss = -loglik
    }
}

extern "C" void kernel_launch(void* const* d_in, const int* in_sizes, int n_in,
                              void* d_out, int out_size, void* d_ws, size_t ws_size,
                              hipStream_t stream)
{
    (void)in_sizes; (void)n_in; (void)ws_size; (void)out_size;
    const float* counts       = (const float*)d_in[0];
    const float* theta_params = (const float*)d_in[1];
    const float* beta         = (const float*)d_in[2];
    float* out = (float*)d_out;
    u32x4* Bf  = (u32x4*)d_ws;        // 112 KB fragment-ordered log-theta bf16

    // prep: 112 theta/Bf blocks + 157 beta-copy blocks
    mcspace_prep<<<dim3(112 + (KK * TT * SS + 63) / 64), dim3(64), 0, stream>>>(
        theta_params, beta, out, Bf);
    // main: 1024 blocks x 4 waves, per-wave tile streams
    mcspace_main<<<dim3(NBLK), dim3(BLOCKT), 0, stream>>>(
        counts, beta, Bf, out);
}

// Round 6
// 231.889 us; speedup vs baseline: 2.3074x; 1.0219x over previous
//
#include <hip/hip_runtime.h>
#include <math.h>

// Problem constants (from reference)
#define TT 10
#define SS 10
#define RR 2000
#define KK 100
#define OO 500
#define PP (TT*SS*RR)          // 200000 particles
#define NT16 12500             // 16-row tiles
#define NT 7                   // 7 N-tiles of 16 cols -> 112 padded assemblages
#define WAVES 12               // waves per block, 1 block/CU (LDS = 160 KiB exactly)
#define BLOCKT (WAVES*64)      // 768 threads
#define NBLK 256
#define EPSF 1e-6f

typedef float        f32x4  __attribute__((ext_vector_type(4)));
typedef unsigned int u32x4  __attribute__((ext_vector_type(4)));
typedef unsigned int u32x2  __attribute__((ext_vector_type(2)));
typedef __bf16       bf16x8 __attribute__((ext_vector_type(8)));
typedef __bf16       bf16x4 __attribute__((ext_vector_type(4)));

union BFU { bf16x8 v; u32x4 q; };
union BF4 { bf16x4 v; u32x2 q; };

// ---------------------------------------------------------------------------
// Prep: theta = softmax -> out[1..50001); beta copy -> out[50001..);
// out[0] = 0; tile counter (d_ws) = 0.
// ---------------------------------------------------------------------------
__global__ __launch_bounds__(64) void mcspace_prep(
    const float* __restrict__ theta_params,
    const float* __restrict__ beta,
    float* __restrict__ out,
    unsigned* __restrict__ cnt)
{
    const int b  = blockIdx.x;
    const int ln = threadIdx.x;
    if (b < KK) {
        const float* tp = theta_params + b * OO;
        float x[8];
        #pragma unroll
        for (int j = 0; j < 8; ++j) {
            int o = ln + 64 * j;
            x[j] = (o < OO) ? tp[o] : -INFINITY;
        }
        float mx = x[0];
        #pragma unroll
        for (int j = 1; j < 8; ++j) mx = fmaxf(mx, x[j]);
        #pragma unroll
        for (int w = 1; w < 64; w <<= 1) mx = fmaxf(mx, __shfl_xor(mx, w));
        float e[8], sm = 0.f;
        #pragma unroll
        for (int j = 0; j < 8; ++j) { e[j] = __expf(x[j] - mx); sm += e[j]; }
        #pragma unroll
        for (int w = 1; w < 64; w <<= 1) sm += __shfl_xor(sm, w);
        const float inv = 1.f / sm;
        float* to = out + 1 + b * OO;
        #pragma unroll
        for (int j = 0; j < 8; ++j) {
            int o = ln + 64 * j;
            if (o < OO) to[o] = e[j] * inv;
        }
    } else {
        int idx = (b - KK) * 64 + ln;
        if (idx < KK * TT * SS) out[1 + KK * OO + idx] = beta[idx];
        if (b == KK && ln == 0) { out[0] = 0.f; cnt[0] = 0u; }
    }
}

// ---------------------------------------------------------------------------
// Main: 12 waves/block, 1 block/CU. B (logtheta bf16, swizzled) in LDS.
// Per-wave: dynamic tile fetch; A staged through a private 4 KB quarter-K
// LDS buffer with next-quarter global loads in flight during the k-loop.
// ---------------------------------------------------------------------------
__global__ __launch_bounds__(BLOCKT, 3) void mcspace_main(
    const float* __restrict__ counts,
    const float* __restrict__ theta_params,
    const float* __restrict__ beta,
    unsigned* __restrict__ cnt,
    float* __restrict__ out)
{
    __shared__ char bB[112 * 1024];       // logtheta bf16 [112][512], swizzled (112 KB)
    __shared__ char bA[WAVES * 4096];     // per-wave [16 rows][128 cols] bf16 (48 KB)

    const int tid = threadIdx.x;
    const int wv  = tid >> 6;
    const int ln  = tid & 63;
    const int lo  = ln & 15;
    const int g   = ln >> 4;
    char* wb = bA + wv * 4096;

    // ---- build logtheta bf16 [112][512] in LDS (rows wv + 12*it) ----
    for (int it = 0; it < 10; ++it) {
        const int row = wv + WAVES * it;       // 0..119
        if (row >= 112) break;
        BFU w8; w8.q = (u32x4){0u, 0u, 0u, 0u};
        if (row < KK) {
            const float* tp = theta_params + row * OO;
            float x[8];
            #pragma unroll
            for (int j = 0; j < 8; ++j) {
                int o = ln * 8 + j;
                x[j] = (o < OO) ? tp[o] : -INFINITY;
            }
            float mx = x[0];
            #pragma unroll
            for (int j = 1; j < 8; ++j) mx = fmaxf(mx, x[j]);
            #pragma unroll
            for (int w = 1; w < 64; w <<= 1) mx = fmaxf(mx, __shfl_xor(mx, w));
            float e[8], sm = 0.f;
            #pragma unroll
            for (int j = 0; j < 8; ++j) { e[j] = __expf(x[j] - mx); sm += e[j]; }
            #pragma unroll
            for (int w = 1; w < 64; w <<= 1) sm += __shfl_xor(sm, w);
            const float inv = 1.f / sm;
            #pragma unroll
            for (int j = 0; j < 8; ++j)
                w8.v[j] = (__bf16)__logf(e[j] * inv + EPSF);  // log(theta+EPS)
        }
        *(u32x4*)(bB + row * 1024 + ((ln * 16) ^ ((row & 7) << 4))) = w8.q;
    }
    __syncthreads();

    const int rhalf = ln >> 5;           // row parity within a 2-row load
    const int lq    = ln & 31;           // lane-in-half
    float wacc = 0.f;

    for (;;) {
        unsigned t = 0;
        if (ln == 0) t = atomicAdd(cnt, 1u);
        t = (unsigned)__shfl((int)t, 0);
        if (t >= NT16) break;

        const int ts = (int)t / 125;                 // 125 tiles per (t,s)
        const float* base = counts + (long)t * (16 * OO);

        f32x4 acc[NT];
        #pragma unroll
        for (int nt = 0; nt < NT; ++nt) acc[nt] = (f32x4){0.f, 0.f, 0.f, 0.f};

        // prologue: issue quarter-0 loads (8 x 1KB, 2 rows x 512B each)
        f32x4 v[8];
        #pragma unroll
        for (int i = 0; i < 8; ++i)
            v[i] = *(const f32x4*)(base + (2 * i + rhalf) * OO + lq * 4);

        #pragma unroll
        for (int q = 0; q < 4; ++q) {
            // ---- cvt + swizzled ds_write of current quarter ----
            #pragma unroll
            for (int i = 0; i < 8; ++i) {
                const int row = 2 * i + rhalf;
                BF4 w;
                #pragma unroll
                for (int c = 0; c < 4; ++c) w.v[c] = (__bf16)v[i][c];
                *(u32x2*)(wb + row * 256 + ((lq * 8) ^ ((row & 7) << 4))) = w.q;
            }
            // ---- issue next quarter's loads (fly during k-loop) ----
            if (q < 3) {
                const int c0n = (q + 1) * 128;
                #pragma unroll
                for (int i = 0; i < 8; ++i) {
                    const int row = 2 * i + rhalf;
                    if (q + 1 == 3 && lq >= 29)      // cols 500..511 -> zero pad
                        v[i] = (f32x4){0.f, 0.f, 0.f, 0.f};
                    else
                        v[i] = *(const f32x4*)(base + row * OO + c0n + lq * 4);
                }
            }
            // ---- k-loop over this quarter: 4 steps of K=32 ----
            #pragma unroll
            for (int ks = 0; ks < 4; ++ks) {
                const int K0 = q * 4 + ks;
                BFU av;
                av.q = *(const u32x4*)(wb + lo * 256 + ((ks * 64 + g * 16) ^ ((lo & 7) << 4)));
                #pragma unroll
                for (int nt = 0; nt < NT; ++nt) {
                    const int row = nt * 16 + lo;
                    BFU bv;
                    bv.q = *(const u32x4*)(bB + row * 1024 + ((K0 * 64 + g * 16) ^ ((row & 7) << 4)));
                    acc[nt] = __builtin_amdgcn_mfma_f32_16x16x32_bf16(av.v, bv.v, acc[nt], 0, 0, 0);
                }
            }
        }

        // ---- beta-weighted logsumexp (in-register, R1-verified layout) ----
        float bet[NT];
        #pragma unroll
        for (int nt = 0; nt < NT; ++nt) {
            int j = nt * 16 + lo;
            bet[nt] = (j < KK) ? beta[j * (TT * SS) + ts] : 0.f;
        }
        float mrow[4] = {-INFINITY, -INFINITY, -INFINITY, -INFINITY};
        #pragma unroll
        for (int nt = 0; nt < NT; ++nt) {
            const bool valid = (nt * 16 + lo) < KK;
            #pragma unroll
            for (int r = 0; r < 4; ++r)
                mrow[r] = fmaxf(mrow[r], valid ? acc[nt][r] : -INFINITY);
        }
        #pragma unroll
        for (int w = 1; w < 16; w <<= 1) {
            #pragma unroll
            for (int r = 0; r < 4; ++r)
                mrow[r] = fmaxf(mrow[r], __shfl_xor(mrow[r], w));
        }
        float srow[4] = {0.f, 0.f, 0.f, 0.f};
        #pragma unroll
        for (int nt = 0; nt < NT; ++nt) {
            const bool valid = (nt * 16 + lo) < KK;
            #pragma unroll
            for (int r = 0; r < 4; ++r)
                srow[r] += bet[nt] * __expf(valid ? (acc[nt][r] - mrow[r]) : -INFINITY);
        }
        #pragma unroll
        for (int w = 1; w < 16; w <<= 1) {
            #pragma unroll
            for (int r = 0; r < 4; ++r)
                srow[r] += __shfl_xor(srow[r], w);
        }
        if (lo == 0) {
            #pragma unroll
            for (int r = 0; r < 4; ++r)
                wacc += mrow[r] + __logf(srow[r] + EPSF);
        }
    }

    // ---- deterministic block reduction (reuse bA), one atomic per block ----
    #pragma unroll
    for (int w = 1; w < 64; w <<= 1) wacc += __shfl_xor(wacc, w);
    __syncthreads();                       // all waves done with bA
    float* red = (float*)bA;
    if (ln == 0) red[wv] = wacc;
    __syncthreads();
    if (tid == 0) {
        float s = 0.f;
        #pragma unroll
        for (int i = 0; i < WAVES; ++i) s += red[i];
        atomicAdd(out, -s);   // elbo_loss = -loglik
    }
}

extern "C" void kernel_launch(void* const* d_in, const int* in_sizes, int n_in,
                              void* d_out, int out_size, void* d_ws, size_t ws_size,
                              hipStream_t stream)
{
    (void)in_sizes; (void)n_in; (void)ws_size; (void)out_size;
    const float* counts       = (const float*)d_in[0];
    const float* theta_params = (const float*)d_in[1];
    const float* beta         = (const float*)d_in[2];
    float* out    = (float*)d_out;
    unsigned* cnt = (unsigned*)d_ws;      // dynamic tile counter (zeroed by prep)

    // prep: 100 softmax rows + 157 beta-copy blocks (one wave each)
    mcspace_prep<<<dim3(KK + (KK * TT * SS + 63) / 64), dim3(64), 0, stream>>>(
        theta_params, beta, out, cnt);
    // main: 256 blocks x 12 waves (1 block/CU), dynamic tile distribution
    mcspace_main<<<dim3(NBLK), dim3(BLOCKT), 0, stream>>>(
        counts, theta_params, beta, cnt, out);
}